// Round 9
// baseline (153.182 us; speedup 1.0000x reference)
//
#include <hip/hip_runtime.h>
#include <hip/hip_bf16.h>

#define NN 100000
#define NE 800000
#define EBLK 391        // ceil(NE/2048)
#define NBUK 196        // ceil(NN/512), bucket = dst >> 9
#define GH_STRIDE 392   // padded EBLK

typedef __attribute__((ext_vector_type(8))) short bf16x8;
typedef __attribute__((ext_vector_type(4))) float f32x4;

__device__ __forceinline__ unsigned short f2b(float f) {
  unsigned int x = __float_as_uint(f);
  return (unsigned short)((x + 0x7fffu + ((x >> 16) & 1u)) >> 16);
}
__device__ __forceinline__ float b2f(short us) {
  return __uint_as_float(((unsigned int)(unsigned short)us) << 16);
}
__device__ __forceinline__ void acc8(float* acc, bf16x8 v) {
#pragma unroll
  for (int i = 0; i < 8; ++i) acc[i] += b2f(v[i]);
}

// ---------------- atomic-free CSR build ----------------
static __global__ __launch_bounds__(256) void k_hist(const int* __restrict__ dst, int* __restrict__ ghistT) {
  __shared__ int hist[NBUK];
  int tid = threadIdx.x, blk = blockIdx.x;
  for (int i = tid; i < NBUK; i += 256) hist[i] = 0;
  __syncthreads();
  int base = blk * 2048;
#pragma unroll
  for (int i = 0; i < 8; ++i) {
    int e = base + tid + 256 * i;
    if (e < NE) atomicAdd(&hist[dst[e] >> 9], 1);
  }
  __syncthreads();
  for (int i = tid; i < NBUK; i += 256) ghistT[i * GH_STRIDE + blk] = hist[i];
}

static __global__ __launch_bounds__(64) void k_gscan(int* __restrict__ ghistT, int* __restrict__ btot) {
  int b = blockIdx.x, lane = threadIdx.x;
  int carry = 0;
#pragma unroll
  for (int c = 0; c < (EBLK + 63) / 64; ++c) {
    int e = c * 64 + lane;
    int v = (e < EBLK) ? ghistT[b * GH_STRIDE + e] : 0;
    int s = v;
    for (int off = 1; off < 64; off <<= 1) {
      int t = __shfl_up(s, off);
      if (lane >= off) s += t;
    }
    if (e < EBLK) ghistT[b * GH_STRIDE + e] = carry + s - v;
    carry += __shfl(s, 63);
  }
  if (lane == 0) btot[b] = carry;
}

static __global__ void k_btot(const int* __restrict__ btot, int* __restrict__ bstart) {
  __shared__ int sd[256];
  int tid = threadIdx.x;
  int v = (tid < NBUK) ? btot[tid] : 0;
  sd[tid] = v;
  __syncthreads();
  for (int off = 1; off < 256; off <<= 1) {
    int t = (tid >= off) ? sd[tid - off] : 0;
    __syncthreads();
    sd[tid] += t;
    __syncthreads();
  }
  if (tid <= NBUK) bstart[tid] = sd[tid] - v;
}

// pack = (src << 9) | (dst & 511); bucket kept alongside in LDS for write-out
static __global__ __launch_bounds__(256) void k_scatter(const int* __restrict__ src, const int* __restrict__ dst,
                                                        const int* __restrict__ ghistT, const int* __restrict__ bstart,
                                                        int* __restrict__ ebuf) {
  __shared__ int hist[256];
  __shared__ int lstart[256];
  __shared__ int cur[NBUK];
  __shared__ int2 sbuf[2048];
  int tid = threadIdx.x, blk = blockIdx.x;
  hist[tid] = 0;
  __syncthreads();
  int base = blk * 2048;
  int dd[8], ss[8];
#pragma unroll
  for (int i = 0; i < 8; ++i) {
    int e = base + tid + 256 * i;
    if (e < NE) {
      dd[i] = dst[e]; ss[i] = src[e];
      atomicAdd(&hist[dd[i] >> 9], 1);
    } else dd[i] = -1;
  }
  __syncthreads();
  int v = hist[tid];
  lstart[tid] = v;
  __syncthreads();
  for (int off = 1; off < 256; off <<= 1) {
    int t = (tid >= off) ? lstart[tid - off] : 0;
    __syncthreads();
    lstart[tid] += t;
    __syncthreads();
  }
  int excl = lstart[tid] - v;
  __syncthreads();
  lstart[tid] = excl;
  if (tid < NBUK) cur[tid] = 0;
  __syncthreads();
#pragma unroll
  for (int i = 0; i < 8; ++i) {
    if (dd[i] >= 0) {
      int b = dd[i] >> 9;
      int p = atomicAdd(&cur[b], 1);
      sbuf[lstart[b] + p] = make_int2((ss[i] << 9) | (dd[i] & 511), b);
    }
  }
  __syncthreads();
  int m = NE - base; if (m > 2048) m = 2048;
#pragma unroll
  for (int i = 0; i < 8; ++i) {
    int j = tid + 256 * i;
    if (j < m) {
      int2 e = sbuf[j];
      int b = e.y;
      int gpos = bstart[b] + ghistT[b * GH_STRIDE + blk] + (j - lstart[b]);
      ebuf[gpos] = e.x;
    }
  }
}

static __global__ __launch_bounds__(256) void k_bucket(const int* __restrict__ ebuf, const int* __restrict__ bstart,
                                                       int2* __restrict__ rc, float* __restrict__ dis,
                                                       int* __restrict__ col_idx) {
  __shared__ int cnt[512];
  __shared__ int lrs[512];
  __shared__ int sd[256];
  int b = blockIdx.x, tid = threadIdx.x;
  int base_n = b << 9;
  int ebeg = bstart[b], eend = bstart[b + 1];
  int m = eend - ebeg;
  cnt[tid] = 0; cnt[tid + 256] = 0;
  __syncthreads();
  for (int j = tid; j < m; j += 256) atomicAdd(&cnt[ebuf[ebeg + j] & 511], 1);
  __syncthreads();
  int v0 = cnt[2 * tid], v1 = cnt[2 * tid + 1];
  int s = v0 + v1;
  sd[tid] = s;
  __syncthreads();
  for (int off = 1; off < 256; off <<= 1) {
    int t = (tid >= off) ? sd[tid - off] : 0;
    __syncthreads();
    sd[tid] += t;
    __syncthreads();
  }
  int excl = sd[tid] - s;
  lrs[2 * tid] = excl;
  lrs[2 * tid + 1] = excl + v0;
  __syncthreads();
  for (int i = tid; i < 512; i += 256) {
    int n = base_n + i;
    if (n < NN) {
      int c = cnt[i];
      rc[n] = make_int2(ebeg + lrs[i], c);
      dis[n] = 1.0f / sqrtf((float)c + 1.0f);
    }
  }
  for (int i = tid; i < 512; i += 256) cnt[i] = lrs[i];
  __syncthreads();
  for (int j = tid; j < m; j += 256) {
    int e = ebuf[ebeg + j];
    int p = atomicAdd(&cnt[e & 511], 1);
    col_idx[ebeg + p] = e >> 9;
  }
}

// ---------------- weight convert + transpose to bf16 ----------------
static __global__ __launch_bounds__(256) void k_wconv(
    const float* __restrict__ W1, const float* __restrict__ W2, const float* __restrict__ W3,
    const float* __restrict__ Wf1, const float* __restrict__ Wf2, const float* __restrict__ Wf3,
    short* __restrict__ W1t, short* __restrict__ W2t, short* __restrict__ W3t,
    short* __restrict__ Wf1t, short* __restrict__ Wf2t, short* __restrict__ Wf3t) {
  int b = blockIdx.x, tid = threadIdx.x;
  if (b < 5) {
    const float* W = (b == 0) ? W1 : (b == 1) ? W2 : (b == 2) ? W3 : (b == 3) ? Wf1 : Wf2;
    short* Wt = (b == 0) ? W1t : (b == 1) ? W2t : (b == 2) ? W3t : (b == 3) ? Wf1t : Wf2t;
#pragma unroll
    for (int i = 0; i < 16; ++i) {
      int idx = tid + 256 * i;       // = k*64 + n
      int k = idx >> 6, nn = idx & 63;
      Wt[nn * 64 + k] = (short)f2b(W[idx]);
    }
  } else {
#pragma unroll
    for (int i = 0; i < 4; ++i) {
      int idx = tid + 256 * i;       // = k*16 + n
      int k = idx >> 4, nn = idx & 15;
      Wf3t[nn * 64 + k] = (short)f2b(Wf3[idx]);
    }
  }
}

__device__ __forceinline__ bf16x8 load_a_frag_f32(const float* __restrict__ p, bool valid) {
  float4 f0 = valid ? *(const float4*)p : make_float4(0.f, 0.f, 0.f, 0.f);
  float4 f1 = valid ? *(const float4*)(p + 4) : make_float4(0.f, 0.f, 0.f, 0.f);
  bf16x8 a;
  a[0] = (short)f2b(f0.x); a[1] = (short)f2b(f0.y); a[2] = (short)f2b(f0.z); a[3] = (short)f2b(f0.w);
  a[4] = (short)f2b(f1.x); a[5] = (short)f2b(f1.y); a[6] = (short)f2b(f1.z); a[7] = (short)f2b(f1.w);
  return a;
}

// shared MFMA body: writes ht (bf16, dis-scaled)
__device__ __forceinline__ void mm_body(bf16x8 a0, bf16x8 a1, const short* __restrict__ Wt,
                                        const float* __restrict__ dis, short* __restrict__ out,
                                        int row0, int rlane, int g, int n) {
  f32x4 acc[4];
#pragma unroll
  for (int t = 0; t < 4; ++t) acc[t] = (f32x4){0.f, 0.f, 0.f, 0.f};
#pragma unroll
  for (int t = 0; t < 4; ++t) {
    bf16x8 b0 = *(const bf16x8*)(Wt + (rlane + 16 * t) * 64 + g * 8);
    bf16x8 b1 = *(const bf16x8*)(Wt + (rlane + 16 * t) * 64 + g * 8 + 32);
    acc[t] = __builtin_amdgcn_mfma_f32_16x16x32_bf16(a0, b0, acc[t], 0, 0, 0);
    acc[t] = __builtin_amdgcn_mfma_f32_16x16x32_bf16(a1, b1, acc[t], 0, 0, 0);
  }
#pragma unroll
  for (int r = 0; r < 4; ++r) {
    int gr = row0 + g * 4 + r;
    if (gr < n) {
      float s = dis[gr];
#pragma unroll
      for (int t = 0; t < 4; ++t)
        out[(size_t)gr * 64 + rlane + 16 * t] = (short)f2b(acc[t][r] * s);
    }
  }
}

// layer-1: f32 input, ht1 = (x @ W1) * dis
static __global__ __launch_bounds__(256) void k_mm1(const float* __restrict__ in, const short* __restrict__ Wt,
                                                    const float* __restrict__ dis, short* __restrict__ out, int n) {
  int tid = threadIdx.x;
  int lane = tid & 63, w = tid >> 6;
  int row0 = blockIdx.x * 64 + w * 16;
  int rlane = lane & 15, g = lane >> 4;
  int arow = row0 + rlane;
  bool av = arow < n;
  const float* ap = in + (size_t)arow * 64 + g * 8;
  bf16x8 a0 = load_a_frag_f32(ap, av);
  bf16x8 a1 = load_a_frag_f32(ap + 32, av);
  mm_body(a0, a1, Wt, dis, out, row0, rlane, g, n);
}

// agg phase: each 8-lane group owns nodes g and g+8. Per 8-edge chunk, ALL 16
// row-loads are issued (unconditional, invalid -> row 0, cache-hot) BEFORE any
// accumulation: 16 outstanding 16B loads/lane = one latency exposure per chunk.
__device__ __forceinline__ void agg_to_lds(const short* __restrict__ ht, const int2* __restrict__ rc,
                                           const int* __restrict__ col_idx, const float* __restrict__ dis,
                                           const float* __restrict__ bias, short (*Hsw)[72],
                                           int row0, int lane, int n) {
  int g = lane >> 3, f = lane & 7;
  float4 b0v = *(const float4*)&bias[f * 8];
  float4 b1v = *(const float4*)&bias[f * 8 + 4];
  float bb[8] = {b0v.x, b0v.y, b0v.z, b0v.w, b1v.x, b1v.y, b1v.z, b1v.w};
  int node0 = row0 + g, node1 = row0 + 8 + g;
  bool nv0 = node0 < n, nv1 = node1 < n;
  int2 rc0 = nv0 ? rc[node0] : make_int2(0, 0);
  int2 rc1 = nv1 ? rc[node1] : make_int2(0, 0);
  int beg0 = rc0.x, cnt0 = rc0.y;
  int beg1 = rc1.x, cnt1 = rc1.y;
  float dis0 = nv0 ? dis[node0] : 0.f;
  float dis1 = nv1 ? dis[node1] : 0.f;
  float acc0[8] = {0.f, 0.f, 0.f, 0.f, 0.f, 0.f, 0.f, 0.f};
  float acc1[8] = {0.f, 0.f, 0.f, 0.f, 0.f, 0.f, 0.f, 0.f};
  if (nv0) acc8(acc0, *(const bf16x8*)(ht + (size_t)node0 * 64 + f * 8));   // self-loop
  if (nv1) acc8(acc1, *(const bf16x8*)(ht + (size_t)node1 * 64 + f * 8));
  int cmax = max(cnt0, cnt1);
  for (int base = 0; base < cmax; base += 8) {
    int idx0 = (base + f < cnt0) ? col_idx[beg0 + base + f] : 0;
    int idx1 = (base + f < cnt1) ? col_idx[beg1 + base + f] : 0;
    int s0[8], s1[8];
#pragma unroll
    for (int e = 0; e < 8; ++e) {
      s0[e] = __shfl(idx0, g * 8 + e);
      s1[e] = __shfl(idx1, g * 8 + e);
    }
    bf16x8 r0[8], r1[8];
#pragma unroll
    for (int e = 0; e < 8; ++e) r0[e] = *(const bf16x8*)(ht + (size_t)s0[e] * 64 + f * 8);
#pragma unroll
    for (int e = 0; e < 8; ++e) r1[e] = *(const bf16x8*)(ht + (size_t)s1[e] * 64 + f * 8);
    int m0 = cnt0 - base; m0 = (m0 < 0) ? 0 : ((m0 > 8) ? 8 : m0);
    int m1 = cnt1 - base; m1 = (m1 < 0) ? 0 : ((m1 > 8) ? 8 : m1);
#pragma unroll
    for (int e = 0; e < 8; ++e) { if (e < m0) acc8(acc0, r0[e]); }
#pragma unroll
    for (int e = 0; e < 8; ++e) { if (e < m1) acc8(acc1, r1[e]); }
  }
  bf16x8 o0, o1;
#pragma unroll
  for (int i = 0; i < 8; ++i) {
    o0[i] = (short)f2b(fmaxf(fmaf(dis0, acc0[i], bb[i]), 0.f));
    o1[i] = (short)f2b(fmaxf(fmaf(dis1, acc1[i], bb[i]), 0.f));
  }
  *(bf16x8*)&Hsw[g][f * 8] = o0;
  *(bf16x8*)&Hsw[8 + g][f * 8] = o1;
}

// fused: agg (layer l) -> matmul (layer l+1), per-wave private, ZERO barriers
static __global__ __launch_bounds__(256) void k_aggmm(const short* __restrict__ ht, const int2* __restrict__ rc,
                                                      const int* __restrict__ col_idx, const float* __restrict__ dis,
                                                      const float* __restrict__ bias, const short* __restrict__ Wt,
                                                      short* __restrict__ out, int n) {
  __shared__ __align__(16) short Hs[4][16][72];
  int tid = threadIdx.x;
  int lane = tid & 63, w = tid >> 6;
  int row0 = blockIdx.x * 64 + w * 16;
  agg_to_lds(ht, rc, col_idx, dis, bias, Hs[w], row0, lane, n);
  int rlane = lane & 15, g = lane >> 4;
  bf16x8 a0 = *(const bf16x8*)&Hs[w][rlane][g * 8];
  bf16x8 a1 = *(const bf16x8*)&Hs[w][rlane][g * 8 + 32];
  mm_body(a0, a1, Wt, dis, out, row0, rlane, g, n);
}

// fused: agg (layer 3) -> MLP head -> log_softmax, per-wave private, ZERO barriers
static __global__ __launch_bounds__(256) void k_aggdense(const short* __restrict__ ht, const int2* __restrict__ rc,
    const int* __restrict__ col_idx, const float* __restrict__ dis, const float* __restrict__ bias,
    const short* __restrict__ W1t, const float* __restrict__ bf1,
    const short* __restrict__ W2t, const float* __restrict__ bf2,
    const short* __restrict__ W3t, const float* __restrict__ bf3,
    float* __restrict__ out, int n) {
  __shared__ __align__(16) short Hs[4][16][72];
  int tid = threadIdx.x;
  int lane = tid & 63, w = tid >> 6;
  int row0 = blockIdx.x * 64 + w * 16;
  agg_to_lds(ht, rc, col_idx, dis, bias, Hs[w], row0, lane, n);
  int rlane = lane & 15, g = lane >> 4;
  bf16x8 a0 = *(const bf16x8*)&Hs[w][rlane][g * 8];
  bf16x8 a1 = *(const bf16x8*)&Hs[w][rlane][g * 8 + 32];
  f32x4 acc[4];
#pragma unroll
  for (int t = 0; t < 4; ++t) acc[t] = (f32x4){0.f, 0.f, 0.f, 0.f};
#pragma unroll
  for (int t = 0; t < 4; ++t) {
    bf16x8 b0 = *(const bf16x8*)(W1t + (rlane + 16 * t) * 64 + g * 8);
    bf16x8 b1 = *(const bf16x8*)(W1t + (rlane + 16 * t) * 64 + g * 8 + 32);
    acc[t] = __builtin_amdgcn_mfma_f32_16x16x32_bf16(a0, b0, acc[t], 0, 0, 0);
    acc[t] = __builtin_amdgcn_mfma_f32_16x16x32_bf16(a1, b1, acc[t], 0, 0, 0);
  }
#pragma unroll
  for (int t = 0; t < 4; ++t) {
    float bb = bf1[16 * t + rlane];
#pragma unroll
    for (int r = 0; r < 4; ++r)
      Hs[w][g * 4 + r][16 * t + rlane] = (short)f2b(fmaxf(acc[t][r] + bb, 0.f));
  }
  bf16x8 c0 = *(const bf16x8*)&Hs[w][rlane][g * 8];
  bf16x8 c1 = *(const bf16x8*)&Hs[w][rlane][g * 8 + 32];
  f32x4 acc2[4];
#pragma unroll
  for (int t = 0; t < 4; ++t) acc2[t] = (f32x4){0.f, 0.f, 0.f, 0.f};
#pragma unroll
  for (int t = 0; t < 4; ++t) {
    bf16x8 b0 = *(const bf16x8*)(W2t + (rlane + 16 * t) * 64 + g * 8);
    bf16x8 b1 = *(const bf16x8*)(W2t + (rlane + 16 * t) * 64 + g * 8 + 32);
    acc2[t] = __builtin_amdgcn_mfma_f32_16x16x32_bf16(c0, b0, acc2[t], 0, 0, 0);
    acc2[t] = __builtin_amdgcn_mfma_f32_16x16x32_bf16(c1, b1, acc2[t], 0, 0, 0);
  }
#pragma unroll
  for (int t = 0; t < 4; ++t) {
    float bb = bf2[16 * t + rlane];
#pragma unroll
    for (int r = 0; r < 4; ++r)
      Hs[w][g * 4 + r][16 * t + rlane] = (short)f2b(fmaxf(acc2[t][r] + bb, 0.f));
  }
  bf16x8 d0 = *(const bf16x8*)&Hs[w][rlane][g * 8];
  bf16x8 d1 = *(const bf16x8*)&Hs[w][rlane][g * 8 + 32];
  bf16x8 e0 = *(const bf16x8*)(W3t + rlane * 64 + g * 8);
  bf16x8 e1 = *(const bf16x8*)(W3t + rlane * 64 + g * 8 + 32);
  f32x4 z = (f32x4){0.f, 0.f, 0.f, 0.f};
  z = __builtin_amdgcn_mfma_f32_16x16x32_bf16(d0, e0, z, 0, 0, 0);
  z = __builtin_amdgcn_mfma_f32_16x16x32_bf16(d1, e1, z, 0, 0, 0);
  float bsc = bf3[rlane];
#pragma unroll
  for (int r = 0; r < 4; ++r) {
    float zz = z[r] + bsc;
    float mx = zz;
    mx = fmaxf(mx, __shfl_xor(mx, 1));
    mx = fmaxf(mx, __shfl_xor(mx, 2));
    mx = fmaxf(mx, __shfl_xor(mx, 4));
    mx = fmaxf(mx, __shfl_xor(mx, 8));
    float ex = __expf(zz - mx);
    ex += __shfl_xor(ex, 1);
    ex += __shfl_xor(ex, 2);
    ex += __shfl_xor(ex, 4);
    ex += __shfl_xor(ex, 8);
    float lse = mx + __logf(ex);
    int gr = row0 + g * 4 + r;
    if (gr < n) out[(size_t)gr * 16 + rlane] = zz - lse;
  }
}

extern "C" void kernel_launch(void* const* d_in, const int* in_sizes, int n_in,
                              void* d_out, int out_size, void* d_ws, size_t ws_size,
                              hipStream_t stream) {
  (void)in_sizes; (void)n_in; (void)out_size; (void)ws_size;
  const float* x   = (const float*)d_in[0];
  const int*   ei  = (const int*)d_in[1];
  const float* W1  = (const float*)d_in[2];
  const float* b1  = (const float*)d_in[3];
  const float* W2  = (const float*)d_in[4];
  const float* b2  = (const float*)d_in[5];
  const float* W3  = (const float*)d_in[6];
  const float* b3  = (const float*)d_in[7];
  const float* Wf1 = (const float*)d_in[8];
  const float* bf1 = (const float*)d_in[9];
  const float* Wf2 = (const float*)d_in[10];
  const float* bf2 = (const float*)d_in[11];
  const float* Wf3 = (const float*)d_in[12];
  const float* bf3 = (const float*)d_in[13];
  float* outp = (float*)d_out;
  const int* srcp = ei;
  const int* dstp = ei + NE;

  char* ws = (char*)d_ws;
  size_t off = 0;
  auto alloc = [&](size_t bytes) { void* p = ws + off; off = (off + bytes + 255) & ~(size_t)255; return p; };
  int2*  rc     = (int2*)alloc((size_t)NN * 8);
  float* dis    = (float*)alloc((size_t)NN * 4);
  int*   colidx = (int*)alloc((size_t)NE * 4);
  int*   ghistT = (int*)alloc((size_t)NBUK * GH_STRIDE * 4);
  int*   btot   = (int*)alloc(256 * 4);
  int*   bstart = (int*)alloc(256 * 4);
  short* W1t    = (short*)alloc(4096 * 2);
  short* W2t    = (short*)alloc(4096 * 2);
  short* W3t    = (short*)alloc(4096 * 2);
  short* Wf1t   = (short*)alloc(4096 * 2);
  short* Wf2t   = (short*)alloc(4096 * 2);
  short* Wf3t   = (short*)alloc(1024 * 2);
  short* bufA   = (short*)alloc((size_t)NN * 64 * 2);
  short* bufB   = (short*)alloc((size_t)NN * 64 * 2);
  int*   ebuf   = (int*)alloc((size_t)NE * 4);

  int gMM = (NN + 63) / 64;      // 1563

  k_wconv<<<6, 256, 0, stream>>>(W1, W2, W3, Wf1, Wf2, Wf3, W1t, W2t, W3t, Wf1t, Wf2t, Wf3t);
  k_hist<<<EBLK, 256, 0, stream>>>(dstp, ghistT);
  k_gscan<<<NBUK, 64, 0, stream>>>(ghistT, btot);
  k_btot<<<1, 256, 0, stream>>>(btot, bstart);
  k_scatter<<<EBLK, 256, 0, stream>>>(srcp, dstp, ghistT, bstart, ebuf);
  k_bucket<<<NBUK, 256, 0, stream>>>(ebuf, bstart, rc, dis, colidx);

  // ht1 = (x @ W1) * dis
  k_mm1<<<gMM, 256, 0, stream>>>(x, W1t, dis, bufB, NN);
  // h1 = relu(dis*(agg ht1) + b1); ht2 = (h1 @ W2) * dis
  k_aggmm<<<gMM, 256, 0, stream>>>(bufB, rc, colidx, dis, b1, W2t, bufA, NN);
  // h2 = relu(dis*(agg ht2) + b2); ht3 = (h2 @ W3) * dis
  k_aggmm<<<gMM, 256, 0, stream>>>(bufA, rc, colidx, dis, b2, W3t, bufB, NN);
  // h3 = relu(dis*(agg ht3) + b3); out = log_softmax(MLP(h3))
  k_aggdense<<<gMM, 256, 0, stream>>>(bufB, rc, colidx, dis, b3,
                                      Wf1t, bf1, Wf2t, bf2, Wf3t, bf3, outp, NN);
}

// Round 10
// 147.303 us; speedup vs baseline: 1.0399x; 1.0399x over previous
//
#include <hip/hip_runtime.h>
#include <hip/hip_bf16.h>

#define NN 100000
#define NE 800000
#define EBLK 391        // ceil(NE/2048)
#define NBUK 196        // ceil(NN/512), bucket = dst >> 9
#define BSTRIDE 6144    // fixed per-bucket capacity (expected 4082 +/- 64)

typedef __attribute__((ext_vector_type(8))) short bf16x8;
typedef __attribute__((ext_vector_type(4))) float f32x4;

__device__ __forceinline__ unsigned short f2b(float f) {
  unsigned int x = __float_as_uint(f);
  return (unsigned short)((x + 0x7fffu + ((x >> 16) & 1u)) >> 16);
}
__device__ __forceinline__ float b2f(short us) {
  return __uint_as_float(((unsigned int)(unsigned short)us) << 16);
}
__device__ __forceinline__ void acc8(float* acc, bf16x8 v) {
#pragma unroll
  for (int i = 0; i < 8; ++i) acc[i] += b2f(v[i]);
}

// ---------------- CSR build: 2 kernels, fixed-stride buckets ----------------
// single pass: LDS bucket-sort 2048 edges, reserve per-bucket space via one
// global atomicAdd per (block,bucket), write packed (src<<9|dst&511).
static __global__ __launch_bounds__(256) void k_scatter(const int* __restrict__ src, const int* __restrict__ dst,
                                                        int* __restrict__ gcur, int* __restrict__ ebuf) {
  __shared__ int hist[256];
  __shared__ int lstart[256];
  __shared__ int gbase[256];
  __shared__ int cur[NBUK];
  __shared__ int2 sbuf[2048];
  int tid = threadIdx.x, blk = blockIdx.x;
  hist[tid] = 0;
  __syncthreads();
  int base = blk * 2048;
  int dd[8], ss[8];
#pragma unroll
  for (int i = 0; i < 8; ++i) {
    int e = base + tid + 256 * i;
    if (e < NE) {
      dd[i] = dst[e]; ss[i] = src[e];
      atomicAdd(&hist[dd[i] >> 9], 1);
    } else dd[i] = -1;
  }
  __syncthreads();
  int v = hist[tid];
  lstart[tid] = v;
  __syncthreads();
  for (int off = 1; off < 256; off <<= 1) {
    int t = (tid >= off) ? lstart[tid - off] : 0;
    __syncthreads();
    lstart[tid] += t;
    __syncthreads();
  }
  int excl = lstart[tid] - v;
  __syncthreads();
  lstart[tid] = excl;
  if (tid < NBUK) {
    cur[tid] = 0;
    gbase[tid] = (v > 0) ? atomicAdd(&gcur[tid], v) : 0;
  }
  __syncthreads();
#pragma unroll
  for (int i = 0; i < 8; ++i) {
    if (dd[i] >= 0) {
      int b = dd[i] >> 9;
      int p = atomicAdd(&cur[b], 1);
      sbuf[lstart[b] + p] = make_int2((ss[i] << 9) | (dd[i] & 511), b);
    }
  }
  __syncthreads();
  int m = NE - base; if (m > 2048) m = 2048;
#pragma unroll
  for (int i = 0; i < 8; ++i) {
    int j = tid + 256 * i;
    if (j < m) {
      int2 e = sbuf[j];
      int b = e.y;
      int gpos = b * BSTRIDE + gbase[b] + (j - lstart[b]);
      ebuf[gpos] = e.x;
    }
  }
}

static __global__ __launch_bounds__(256) void k_bucket(const int* __restrict__ ebuf, const int* __restrict__ gcur,
                                                       int2* __restrict__ rc, float* __restrict__ dis,
                                                       int* __restrict__ col_idx) {
  __shared__ int cnt[512];
  __shared__ int lrs[512];
  __shared__ int sd[256];
  int b = blockIdx.x, tid = threadIdx.x;
  int base_n = b << 9;
  int ebeg = b * BSTRIDE;
  int m = gcur[b];
  cnt[tid] = 0; cnt[tid + 256] = 0;
  __syncthreads();
  for (int j = tid; j < m; j += 256) atomicAdd(&cnt[ebuf[ebeg + j] & 511], 1);
  __syncthreads();
  int v0 = cnt[2 * tid], v1 = cnt[2 * tid + 1];
  int s = v0 + v1;
  sd[tid] = s;
  __syncthreads();
  for (int off = 1; off < 256; off <<= 1) {
    int t = (tid >= off) ? sd[tid - off] : 0;
    __syncthreads();
    sd[tid] += t;
    __syncthreads();
  }
  int excl = sd[tid] - s;
  lrs[2 * tid] = excl;
  lrs[2 * tid + 1] = excl + v0;
  __syncthreads();
  for (int i = tid; i < 512; i += 256) {
    int n = base_n + i;
    if (n < NN) {
      int c = cnt[i];
      rc[n] = make_int2(ebeg + lrs[i], c);
      dis[n] = 1.0f / sqrtf((float)c + 1.0f);
    }
  }
  for (int i = tid; i < 512; i += 256) cnt[i] = lrs[i];
  __syncthreads();
  for (int j = tid; j < m; j += 256) {
    int e = ebuf[ebeg + j];
    int p = atomicAdd(&cnt[e & 511], 1);
    col_idx[ebeg + p] = e >> 9;
  }
}

// ---------------- weight convert + transpose to bf16 ----------------
static __global__ __launch_bounds__(256) void k_wconv(
    const float* __restrict__ W1, const float* __restrict__ W2, const float* __restrict__ W3,
    const float* __restrict__ Wf1, const float* __restrict__ Wf2, const float* __restrict__ Wf3,
    short* __restrict__ W1t, short* __restrict__ W2t, short* __restrict__ W3t,
    short* __restrict__ Wf1t, short* __restrict__ Wf2t, short* __restrict__ Wf3t) {
  int b = blockIdx.x, tid = threadIdx.x;
  if (b < 5) {
    const float* W = (b == 0) ? W1 : (b == 1) ? W2 : (b == 2) ? W3 : (b == 3) ? Wf1 : Wf2;
    short* Wt = (b == 0) ? W1t : (b == 1) ? W2t : (b == 2) ? W3t : (b == 3) ? Wf1t : Wf2t;
#pragma unroll
    for (int i = 0; i < 16; ++i) {
      int idx = tid + 256 * i;       // = k*64 + n
      int k = idx >> 6, nn = idx & 63;
      Wt[nn * 64 + k] = (short)f2b(W[idx]);
    }
  } else {
#pragma unroll
    for (int i = 0; i < 4; ++i) {
      int idx = tid + 256 * i;       // = k*16 + n
      int k = idx >> 4, nn = idx & 15;
      Wf3t[nn * 64 + k] = (short)f2b(Wf3[idx]);
    }
  }
}

__device__ __forceinline__ bf16x8 load_a_frag_f32(const float* __restrict__ p, bool valid) {
  float4 f0 = valid ? *(const float4*)p : make_float4(0.f, 0.f, 0.f, 0.f);
  float4 f1 = valid ? *(const float4*)(p + 4) : make_float4(0.f, 0.f, 0.f, 0.f);
  bf16x8 a;
  a[0] = (short)f2b(f0.x); a[1] = (short)f2b(f0.y); a[2] = (short)f2b(f0.z); a[3] = (short)f2b(f0.w);
  a[4] = (short)f2b(f1.x); a[5] = (short)f2b(f1.y); a[6] = (short)f2b(f1.z); a[7] = (short)f2b(f1.w);
  return a;
}

// shared MFMA body: writes ht (bf16, dis-scaled)
__device__ __forceinline__ void mm_body(bf16x8 a0, bf16x8 a1, const short* __restrict__ Wt,
                                        const float* __restrict__ dis, short* __restrict__ out,
                                        int row0, int rlane, int g, int n) {
  f32x4 acc[4];
#pragma unroll
  for (int t = 0; t < 4; ++t) acc[t] = (f32x4){0.f, 0.f, 0.f, 0.f};
#pragma unroll
  for (int t = 0; t < 4; ++t) {
    bf16x8 b0 = *(const bf16x8*)(Wt + (rlane + 16 * t) * 64 + g * 8);
    bf16x8 b1 = *(const bf16x8*)(Wt + (rlane + 16 * t) * 64 + g * 8 + 32);
    acc[t] = __builtin_amdgcn_mfma_f32_16x16x32_bf16(a0, b0, acc[t], 0, 0, 0);
    acc[t] = __builtin_amdgcn_mfma_f32_16x16x32_bf16(a1, b1, acc[t], 0, 0, 0);
  }
#pragma unroll
  for (int r = 0; r < 4; ++r) {
    int gr = row0 + g * 4 + r;
    if (gr < n) {
      float s = dis[gr];
#pragma unroll
      for (int t = 0; t < 4; ++t)
        out[(size_t)gr * 64 + rlane + 16 * t] = (short)f2b(acc[t][r] * s);
    }
  }
}

// layer-1: f32 input, ht1 = (x @ W1) * dis
static __global__ __launch_bounds__(256) void k_mm1(const float* __restrict__ in, const short* __restrict__ Wt,
                                                    const float* __restrict__ dis, short* __restrict__ out, int n) {
  int tid = threadIdx.x;
  int lane = tid & 63, w = tid >> 6;
  int row0 = blockIdx.x * 64 + w * 16;
  int rlane = lane & 15, g = lane >> 4;
  int arow = row0 + rlane;
  bool av = arow < n;
  const float* ap = in + (size_t)arow * 64 + g * 8;
  bf16x8 a0 = load_a_frag_f32(ap, av);
  bf16x8 a1 = load_a_frag_f32(ap + 32, av);
  mm_body(a0, a1, Wt, dis, out, row0, rlane, g, n);
}

// agg phase (R8 2-deep version, VGPR-lean): each 8-lane group walks nodes g and
// g+8 in lockstep, 4 gathers in flight, guarded accumulate.
__device__ __forceinline__ void agg_to_lds(const short* __restrict__ ht, const int2* __restrict__ rc,
                                           const int* __restrict__ col_idx, const float* __restrict__ dis,
                                           const float* __restrict__ bias, short (*Hsw)[72],
                                           int row0, int lane, int n) {
  int g = lane >> 3, f = lane & 7;
  float4 b0v = *(const float4*)&bias[f * 8];
  float4 b1v = *(const float4*)&bias[f * 8 + 4];
  float bb[8] = {b0v.x, b0v.y, b0v.z, b0v.w, b1v.x, b1v.y, b1v.z, b1v.w};
  int node0 = row0 + g, node1 = row0 + 8 + g;
  bool nv0 = node0 < n, nv1 = node1 < n;
  int2 rc0 = nv0 ? rc[node0] : make_int2(0, 0);
  int2 rc1 = nv1 ? rc[node1] : make_int2(0, 0);
  int beg0 = rc0.x, cnt0 = rc0.y;
  int beg1 = rc1.x, cnt1 = rc1.y;
  float dis0 = nv0 ? dis[node0] : 0.f;
  float dis1 = nv1 ? dis[node1] : 0.f;
  float acc0[8] = {0.f, 0.f, 0.f, 0.f, 0.f, 0.f, 0.f, 0.f};
  float acc1[8] = {0.f, 0.f, 0.f, 0.f, 0.f, 0.f, 0.f, 0.f};
  if (nv0) acc8(acc0, *(const bf16x8*)(ht + (size_t)node0 * 64 + f * 8));   // self-loop
  if (nv1) acc8(acc1, *(const bf16x8*)(ht + (size_t)node1 * 64 + f * 8));
  int cmax = max(cnt0, cnt1);
  for (int base = 0; base < cmax; base += 8) {
    int idx0 = (base + f < cnt0) ? col_idx[beg0 + base + f] : 0;
    int idx1 = (base + f < cnt1) ? col_idx[beg1 + base + f] : 0;
    int m0 = cnt0 - base; m0 = (m0 < 0) ? 0 : ((m0 > 8) ? 8 : m0);
    int m1 = cnt1 - base; m1 = (m1 < 0) ? 0 : ((m1 > 8) ? 8 : m1);
    int mm = (m0 > m1) ? m0 : m1;
    int e = 0;
    for (; e + 1 < mm; e += 2) {
      int s00 = __shfl(idx0, g * 8 + e);
      int s01 = __shfl(idx0, g * 8 + e + 1);
      int s10 = __shfl(idx1, g * 8 + e);
      int s11 = __shfl(idx1, g * 8 + e + 1);
      bf16x8 r00 = *(const bf16x8*)(ht + (size_t)s00 * 64 + f * 8);
      bf16x8 r10 = *(const bf16x8*)(ht + (size_t)s10 * 64 + f * 8);
      bf16x8 r01 = *(const bf16x8*)(ht + (size_t)s01 * 64 + f * 8);
      bf16x8 r11 = *(const bf16x8*)(ht + (size_t)s11 * 64 + f * 8);
      if (e < m0)     acc8(acc0, r00);
      if (e + 1 < m0) acc8(acc0, r01);
      if (e < m1)     acc8(acc1, r10);
      if (e + 1 < m1) acc8(acc1, r11);
    }
    if (e < mm) {
      int s00 = __shfl(idx0, g * 8 + e);
      int s10 = __shfl(idx1, g * 8 + e);
      bf16x8 r00 = *(const bf16x8*)(ht + (size_t)s00 * 64 + f * 8);
      bf16x8 r10 = *(const bf16x8*)(ht + (size_t)s10 * 64 + f * 8);
      if (e < m0) acc8(acc0, r00);
      if (e < m1) acc8(acc1, r10);
    }
  }
  bf16x8 o0, o1;
#pragma unroll
  for (int i = 0; i < 8; ++i) {
    o0[i] = (short)f2b(fmaxf(fmaf(dis0, acc0[i], bb[i]), 0.f));
    o1[i] = (short)f2b(fmaxf(fmaf(dis1, acc1[i], bb[i]), 0.f));
  }
  *(bf16x8*)&Hsw[g][f * 8] = o0;
  *(bf16x8*)&Hsw[8 + g][f * 8] = o1;
}

// fused: agg -> matmul. 128-thread blocks (2 waves, 32 nodes) for load balance.
static __global__ __launch_bounds__(128) void k_aggmm(const short* __restrict__ ht, const int2* __restrict__ rc,
                                                      const int* __restrict__ col_idx, const float* __restrict__ dis,
                                                      const float* __restrict__ bias, const short* __restrict__ Wt,
                                                      short* __restrict__ out, int n) {
  __shared__ __align__(16) short Hs[2][16][72];
  int tid = threadIdx.x;
  int lane = tid & 63, w = tid >> 6;
  int row0 = blockIdx.x * 32 + w * 16;
  agg_to_lds(ht, rc, col_idx, dis, bias, Hs[w], row0, lane, n);
  int rlane = lane & 15, g = lane >> 4;
  bf16x8 a0 = *(const bf16x8*)&Hs[w][rlane][g * 8];
  bf16x8 a1 = *(const bf16x8*)&Hs[w][rlane][g * 8 + 32];
  mm_body(a0, a1, Wt, dis, out, row0, rlane, g, n);
}

// fused: agg -> MLP head -> log_softmax. 128-thread blocks.
static __global__ __launch_bounds__(128) void k_aggdense(const short* __restrict__ ht, const int2* __restrict__ rc,
    const int* __restrict__ col_idx, const float* __restrict__ dis, const float* __restrict__ bias,
    const short* __restrict__ W1t, const float* __restrict__ bf1,
    const short* __restrict__ W2t, const float* __restrict__ bf2,
    const short* __restrict__ W3t, const float* __restrict__ bf3,
    float* __restrict__ out, int n) {
  __shared__ __align__(16) short Hs[2][16][72];
  int tid = threadIdx.x;
  int lane = tid & 63, w = tid >> 6;
  int row0 = blockIdx.x * 32 + w * 16;
  agg_to_lds(ht, rc, col_idx, dis, bias, Hs[w], row0, lane, n);
  int rlane = lane & 15, g = lane >> 4;
  bf16x8 a0 = *(const bf16x8*)&Hs[w][rlane][g * 8];
  bf16x8 a1 = *(const bf16x8*)&Hs[w][rlane][g * 8 + 32];
  f32x4 acc[4];
#pragma unroll
  for (int t = 0; t < 4; ++t) acc[t] = (f32x4){0.f, 0.f, 0.f, 0.f};
#pragma unroll
  for (int t = 0; t < 4; ++t) {
    bf16x8 b0 = *(const bf16x8*)(W1t + (rlane + 16 * t) * 64 + g * 8);
    bf16x8 b1 = *(const bf16x8*)(W1t + (rlane + 16 * t) * 64 + g * 8 + 32);
    acc[t] = __builtin_amdgcn_mfma_f32_16x16x32_bf16(a0, b0, acc[t], 0, 0, 0);
    acc[t] = __builtin_amdgcn_mfma_f32_16x16x32_bf16(a1, b1, acc[t], 0, 0, 0);
  }
#pragma unroll
  for (int t = 0; t < 4; ++t) {
    float bb = bf1[16 * t + rlane];
#pragma unroll
    for (int r = 0; r < 4; ++r)
      Hs[w][g * 4 + r][16 * t + rlane] = (short)f2b(fmaxf(acc[t][r] + bb, 0.f));
  }
  bf16x8 c0 = *(const bf16x8*)&Hs[w][rlane][g * 8];
  bf16x8 c1 = *(const bf16x8*)&Hs[w][rlane][g * 8 + 32];
  f32x4 acc2[4];
#pragma unroll
  for (int t = 0; t < 4; ++t) acc2[t] = (f32x4){0.f, 0.f, 0.f, 0.f};
#pragma unroll
  for (int t = 0; t < 4; ++t) {
    bf16x8 b0 = *(const bf16x8*)(W2t + (rlane + 16 * t) * 64 + g * 8);
    bf16x8 b1 = *(const bf16x8*)(W2t + (rlane + 16 * t) * 64 + g * 8 + 32);
    acc2[t] = __builtin_amdgcn_mfma_f32_16x16x32_bf16(c0, b0, acc2[t], 0, 0, 0);
    acc2[t] = __builtin_amdgcn_mfma_f32_16x16x32_bf16(c1, b1, acc2[t], 0, 0, 0);
  }
#pragma unroll
  for (int t = 0; t < 4; ++t) {
    float bb = bf2[16 * t + rlane];
#pragma unroll
    for (int r = 0; r < 4; ++r)
      Hs[w][g * 4 + r][16 * t + rlane] = (short)f2b(fmaxf(acc2[t][r] + bb, 0.f));
  }
  bf16x8 d0 = *(const bf16x8*)&Hs[w][rlane][g * 8];
  bf16x8 d1 = *(const bf16x8*)&Hs[w][rlane][g * 8 + 32];
  bf16x8 e0 = *(const bf16x8*)(W3t + rlane * 64 + g * 8);
  bf16x8 e1 = *(const bf16x8*)(W3t + rlane * 64 + g * 8 + 32);
  f32x4 z = (f32x4){0.f, 0.f, 0.f, 0.f};
  z = __builtin_amdgcn_mfma_f32_16x16x32_bf16(d0, e0, z, 0, 0, 0);
  z = __builtin_amdgcn_mfma_f32_16x16x32_bf16(d1, e1, z, 0, 0, 0);
  float bsc = bf3[rlane];
#pragma unroll
  for (int r = 0; r < 4; ++r) {
    float zz = z[r] + bsc;
    float mx = zz;
    mx = fmaxf(mx, __shfl_xor(mx, 1));
    mx = fmaxf(mx, __shfl_xor(mx, 2));
    mx = fmaxf(mx, __shfl_xor(mx, 4));
    mx = fmaxf(mx, __shfl_xor(mx, 8));
    float ex = __expf(zz - mx);
    ex += __shfl_xor(ex, 1);
    ex += __shfl_xor(ex, 2);
    ex += __shfl_xor(ex, 4);
    ex += __shfl_xor(ex, 8);
    float lse = mx + __logf(ex);
    int gr = row0 + g * 4 + r;
    if (gr < n) out[(size_t)gr * 16 + rlane] = zz - lse;
  }
}

extern "C" void kernel_launch(void* const* d_in, const int* in_sizes, int n_in,
                              void* d_out, int out_size, void* d_ws, size_t ws_size,
                              hipStream_t stream) {
  (void)in_sizes; (void)n_in; (void)out_size; (void)ws_size;
  const float* x   = (const float*)d_in[0];
  const int*   ei  = (const int*)d_in[1];
  const float* W1  = (const float*)d_in[2];
  const float* b1  = (const float*)d_in[3];
  const float* W2  = (const float*)d_in[4];
  const float* b2  = (const float*)d_in[5];
  const float* W3  = (const float*)d_in[6];
  const float* b3  = (const float*)d_in[7];
  const float* Wf1 = (const float*)d_in[8];
  const float* bf1 = (const float*)d_in[9];
  const float* Wf2 = (const float*)d_in[10];
  const float* bf2 = (const float*)d_in[11];
  const float* Wf3 = (const float*)d_in[12];
  const float* bf3 = (const float*)d_in[13];
  float* outp = (float*)d_out;
  const int* srcp = ei;
  const int* dstp = ei + NE;

  char* ws = (char*)d_ws;
  size_t off = 0;
  auto alloc = [&](size_t bytes) { void* p = ws + off; off = (off + bytes + 255) & ~(size_t)255; return p; };
  int2*  rc     = (int2*)alloc((size_t)NN * 8);
  float* dis    = (float*)alloc((size_t)NN * 4);
  int*   gcur   = (int*)alloc(256 * 4);
  int*   colidx = (int*)alloc((size_t)NBUK * BSTRIDE * 4);
  short* W1t    = (short*)alloc(4096 * 2);
  short* W2t    = (short*)alloc(4096 * 2);
  short* W3t    = (short*)alloc(4096 * 2);
  short* Wf1t   = (short*)alloc(4096 * 2);
  short* Wf2t   = (short*)alloc(4096 * 2);
  short* Wf3t   = (short*)alloc(1024 * 2);
  short* bufA   = (short*)alloc((size_t)NN * 64 * 2);
  short* bufB   = (short*)alloc((size_t)NN * 64 * 2);
  int*   ebuf   = (int*)alloc((size_t)NBUK * BSTRIDE * 4);

  int gMM = (NN + 63) / 64;      // 1563 (256-thread blocks)
  int gAG = (NN + 31) / 32;      // 3125 (128-thread blocks)

  hipMemsetAsync(gcur, 0, 256 * 4, stream);
  k_wconv<<<6, 256, 0, stream>>>(W1, W2, W3, Wf1, Wf2, Wf3, W1t, W2t, W3t, Wf1t, Wf2t, Wf3t);
  k_scatter<<<EBLK, 256, 0, stream>>>(srcp, dstp, gcur, ebuf);
  k_bucket<<<NBUK, 256, 0, stream>>>(ebuf, gcur, rc, dis, colidx);

  // ht1 = (x @ W1) * dis
  k_mm1<<<gMM, 256, 0, stream>>>(x, W1t, dis, bufB, NN);
  // h1 = relu(dis*(agg ht1) + b1); ht2 = (h1 @ W2) * dis
  k_aggmm<<<gAG, 128, 0, stream>>>(bufB, rc, colidx, dis, b1, W2t, bufA, NN);
  // h2 = relu(dis*(agg ht2) + b2); ht3 = (h2 @ W3) * dis
  k_aggmm<<<gAG, 128, 0, stream>>>(bufA, rc, colidx, dis, b2, W3t, bufB, NN);
  // h3 = relu(dis*(agg ht3) + b3); out = log_softmax(MLP(h3))
  k_aggdense<<<gAG, 128, 0, stream>>>(bufB, rc, colidx, dis, b3,
                                      Wf1t, bf1, Wf2t, bf2, Wf3t, bf3, outp, NN);
}

// Round 11
// 137.724 us; speedup vs baseline: 1.1122x; 1.0695x over previous
//
#include <hip/hip_runtime.h>
#include <hip/hip_bf16.h>

#define NN 100000
#define NE 800000
#define EBLK 391        // ceil(NE/2048)
#define NBUK 196        // ceil(NN/512), bucket = dst >> 9
#define BSTRIDE 6144    // fixed per-bucket capacity (expected 4082 +/- 64)

typedef __attribute__((ext_vector_type(8))) short bf16x8;
typedef __attribute__((ext_vector_type(4))) float f32x4;

__device__ __forceinline__ unsigned short f2b(float f) {
  unsigned int x = __float_as_uint(f);
  return (unsigned short)((x + 0x7fffu + ((x >> 16) & 1u)) >> 16);
}
__device__ __forceinline__ float b2f(short us) {
  return __uint_as_float(((unsigned int)(unsigned short)us) << 16);
}
__device__ __forceinline__ void acc8(float* acc, bf16x8 v) {
#pragma unroll
  for (int i = 0; i < 8; ++i) acc[i] += b2f(v[i]);
}

// ---------------- CSR build (2 kernels) + weight conversion merged ----------------
// blocks 0..EBLK-1: LDS bucket-sort 2048 edges, reserve space via one global
// atomicAdd per (block,bucket), write packed (src<<9|dst&511).
// blocks EBLK..EBLK+5: convert+transpose the 6 weight matrices to bf16.
static __global__ __launch_bounds__(256) void k_scwc(const int* __restrict__ src, const int* __restrict__ dst,
                                                     int* __restrict__ gcur, int* __restrict__ ebuf,
    const float* __restrict__ W1, const float* __restrict__ W2, const float* __restrict__ W3,
    const float* __restrict__ Wf1, const float* __restrict__ Wf2, const float* __restrict__ Wf3,
    short* __restrict__ W1t, short* __restrict__ W2t, short* __restrict__ W3t,
    short* __restrict__ Wf1t, short* __restrict__ Wf2t, short* __restrict__ Wf3t) {
  int tid = threadIdx.x, blk = blockIdx.x;
  if (blk >= EBLK) {
    int b = blk - EBLK;
    if (b < 5) {
      const float* W = (b == 0) ? W1 : (b == 1) ? W2 : (b == 2) ? W3 : (b == 3) ? Wf1 : Wf2;
      short* Wt = (b == 0) ? W1t : (b == 1) ? W2t : (b == 2) ? W3t : (b == 3) ? Wf1t : Wf2t;
#pragma unroll
      for (int i = 0; i < 16; ++i) {
        int idx = tid + 256 * i;       // = k*64 + n
        int k = idx >> 6, nn = idx & 63;
        Wt[nn * 64 + k] = (short)f2b(W[idx]);
      }
    } else {
#pragma unroll
      for (int i = 0; i < 4; ++i) {
        int idx = tid + 256 * i;       // = k*16 + n
        int k = idx >> 4, nn = idx & 15;
        Wf3t[nn * 64 + k] = (short)f2b(Wf3[idx]);
      }
    }
    return;
  }
  __shared__ int hist[256];
  __shared__ int lstart[256];
  __shared__ int gbase[256];
  __shared__ int cur[NBUK];
  __shared__ int2 sbuf[2048];
  hist[tid] = 0;
  __syncthreads();
  int base = blk * 2048;
  int dd[8], ss[8];
#pragma unroll
  for (int i = 0; i < 8; ++i) {
    int e = base + tid + 256 * i;
    if (e < NE) {
      dd[i] = dst[e]; ss[i] = src[e];
      atomicAdd(&hist[dd[i] >> 9], 1);
    } else dd[i] = -1;
  }
  __syncthreads();
  int v = hist[tid];
  lstart[tid] = v;
  __syncthreads();
  for (int off = 1; off < 256; off <<= 1) {
    int t = (tid >= off) ? lstart[tid - off] : 0;
    __syncthreads();
    lstart[tid] += t;
    __syncthreads();
  }
  int excl = lstart[tid] - v;
  __syncthreads();
  lstart[tid] = excl;
  if (tid < NBUK) {
    cur[tid] = 0;
    gbase[tid] = (v > 0) ? atomicAdd(&gcur[tid], v) : 0;
  }
  __syncthreads();
#pragma unroll
  for (int i = 0; i < 8; ++i) {
    if (dd[i] >= 0) {
      int b = dd[i] >> 9;
      int p = atomicAdd(&cur[b], 1);
      sbuf[lstart[b] + p] = make_int2((ss[i] << 9) | (dd[i] & 511), b);
    }
  }
  __syncthreads();
  int m = NE - base; if (m > 2048) m = 2048;
#pragma unroll
  for (int i = 0; i < 8; ++i) {
    int j = tid + 256 * i;
    if (j < m) {
      int2 e = sbuf[j];
      int b = e.y;
      int gpos = b * BSTRIDE + gbase[b] + (j - lstart[b]);
      ebuf[gpos] = e.x;
    }
  }
}

static __global__ __launch_bounds__(256) void k_bucket(const int* __restrict__ ebuf, const int* __restrict__ gcur,
                                                       int2* __restrict__ rc, float* __restrict__ dis,
                                                       int* __restrict__ col_idx) {
  __shared__ int cnt[512];
  __shared__ int lrs[512];
  __shared__ int sd[256];
  int b = blockIdx.x, tid = threadIdx.x;
  int base_n = b << 9;
  int ebeg = b * BSTRIDE;
  int m = gcur[b];
  cnt[tid] = 0; cnt[tid + 256] = 0;
  __syncthreads();
  for (int j = tid; j < m; j += 256) atomicAdd(&cnt[ebuf[ebeg + j] & 511], 1);
  __syncthreads();
  int v0 = cnt[2 * tid], v1 = cnt[2 * tid + 1];
  int s = v0 + v1;
  sd[tid] = s;
  __syncthreads();
  for (int off = 1; off < 256; off <<= 1) {
    int t = (tid >= off) ? sd[tid - off] : 0;
    __syncthreads();
    sd[tid] += t;
    __syncthreads();
  }
  int excl = sd[tid] - s;
  lrs[2 * tid] = excl;
  lrs[2 * tid + 1] = excl + v0;
  __syncthreads();
  for (int i = tid; i < 512; i += 256) {
    int n = base_n + i;
    if (n < NN) {
      int c = cnt[i];
      rc[n] = make_int2(ebeg + lrs[i], c);
      dis[n] = 1.0f / sqrtf((float)c + 1.0f);
    }
  }
  for (int i = tid; i < 512; i += 256) cnt[i] = lrs[i];
  __syncthreads();
  for (int j = tid; j < m; j += 256) {
    int e = ebuf[ebeg + j];
    int p = atomicAdd(&cnt[e & 511], 1);
    col_idx[ebeg + p] = e >> 9;
  }
}

__device__ __forceinline__ bf16x8 load_a_frag_f32(const float* __restrict__ p, bool valid) {
  float4 f0 = valid ? *(const float4*)p : make_float4(0.f, 0.f, 0.f, 0.f);
  float4 f1 = valid ? *(const float4*)(p + 4) : make_float4(0.f, 0.f, 0.f, 0.f);
  bf16x8 a;
  a[0] = (short)f2b(f0.x); a[1] = (short)f2b(f0.y); a[2] = (short)f2b(f0.z); a[3] = (short)f2b(f0.w);
  a[4] = (short)f2b(f1.x); a[5] = (short)f2b(f1.y); a[6] = (short)f2b(f1.z); a[7] = (short)f2b(f1.w);
  return a;
}

// shared MFMA body: writes ht (bf16, dis-scaled)
__device__ __forceinline__ void mm_body(bf16x8 a0, bf16x8 a1, const short* __restrict__ Wt,
                                        const float* __restrict__ dis, short* __restrict__ out,
                                        int row0, int rlane, int g, int n) {
  f32x4 acc[4];
#pragma unroll
  for (int t = 0; t < 4; ++t) acc[t] = (f32x4){0.f, 0.f, 0.f, 0.f};
#pragma unroll
  for (int t = 0; t < 4; ++t) {
    bf16x8 b0 = *(const bf16x8*)(Wt + (rlane + 16 * t) * 64 + g * 8);
    bf16x8 b1 = *(const bf16x8*)(Wt + (rlane + 16 * t) * 64 + g * 8 + 32);
    acc[t] = __builtin_amdgcn_mfma_f32_16x16x32_bf16(a0, b0, acc[t], 0, 0, 0);
    acc[t] = __builtin_amdgcn_mfma_f32_16x16x32_bf16(a1, b1, acc[t], 0, 0, 0);
  }
#pragma unroll
  for (int r = 0; r < 4; ++r) {
    int gr = row0 + g * 4 + r;
    if (gr < n) {
      float s = dis[gr];
#pragma unroll
      for (int t = 0; t < 4; ++t)
        out[(size_t)gr * 64 + rlane + 16 * t] = (short)f2b(acc[t][r] * s);
    }
  }
}

// layer-1: f32 input, ht1 = (x @ W1) * dis
static __global__ __launch_bounds__(256) void k_mm1(const float* __restrict__ in, const short* __restrict__ Wt,
                                                    const float* __restrict__ dis, short* __restrict__ out, int n) {
  int tid = threadIdx.x;
  int lane = tid & 63, w = tid >> 6;
  int row0 = blockIdx.x * 64 + w * 16;
  int rlane = lane & 15, g = lane >> 4;
  int arow = row0 + rlane;
  bool av = arow < n;
  const float* ap = in + (size_t)arow * 64 + g * 8;
  bf16x8 a0 = load_a_frag_f32(ap, av);
  bf16x8 a1 = load_a_frag_f32(ap + 32, av);
  mm_body(a0, a1, Wt, dis, out, row0, rlane, g, n);
}

// agg (R6-granularity): ONE node per 8-lane group, 8 nodes per wave, 2-deep
// unrolled gather. Wave w of the block writes rows [w*8, w*8+8) of Hs.
__device__ __forceinline__ void agg8_to_lds(const short* __restrict__ ht, const int2* __restrict__ rc,
                                            const int* __restrict__ col_idx, const float* __restrict__ dis,
                                            const float* __restrict__ bias, short (*Hs)[72],
                                            int nodebase, int wrow0, int lane, int n) {
  int g = lane >> 3, f = lane & 7;
  float4 b0v = *(const float4*)&bias[f * 8];
  float4 b1v = *(const float4*)&bias[f * 8 + 4];
  float bb[8] = {b0v.x, b0v.y, b0v.z, b0v.w, b1v.x, b1v.y, b1v.z, b1v.w};
  int node = nodebase + g;
  bool nv = node < n;
  int2 rcv = nv ? rc[node] : make_int2(0, 0);
  int beg = rcv.x, cnt = rcv.y;
  float ds = nv ? dis[node] : 0.f;
  float acc[8] = {0.f, 0.f, 0.f, 0.f, 0.f, 0.f, 0.f, 0.f};
  if (nv) acc8(acc, *(const bf16x8*)(ht + (size_t)node * 64 + f * 8));   // self-loop
  for (int base = 0; base < cnt; base += 8) {
    int mm = cnt - base; if (mm > 8) mm = 8;
    int idx = (base + f < cnt) ? col_idx[beg + base + f] : 0;
    int e = 0;
    for (; e + 1 < mm; e += 2) {
      int s0 = __shfl(idx, g * 8 + e);
      int s1 = __shfl(idx, g * 8 + e + 1);
      bf16x8 r0 = *(const bf16x8*)(ht + (size_t)s0 * 64 + f * 8);
      bf16x8 r1 = *(const bf16x8*)(ht + (size_t)s1 * 64 + f * 8);
      acc8(acc, r0); acc8(acc, r1);
    }
    if (e < mm) {
      int s0 = __shfl(idx, g * 8 + e);
      acc8(acc, *(const bf16x8*)(ht + (size_t)s0 * 64 + f * 8));
    }
  }
  bf16x8 o;
#pragma unroll
  for (int i = 0; i < 8; ++i)
    o[i] = (short)f2b(fmaxf(fmaf(ds, acc[i], bb[i]), 0.f));
  *(bf16x8*)&Hs[wrow0 + g][f * 8] = o;
}

// fused: agg -> matmul. 128 threads / 16 nodes / block (grid 6250 = 12500 waves).
// After one barrier the two waves split the 4 B-column tiles (2 each).
static __global__ __launch_bounds__(128) void k_aggmm(const short* __restrict__ ht, const int2* __restrict__ rc,
                                                      const int* __restrict__ col_idx, const float* __restrict__ dis,
                                                      const float* __restrict__ bias, const short* __restrict__ Wt,
                                                      short* __restrict__ out, int n) {
  __shared__ __align__(16) short Hs[16][72];
  int tid = threadIdx.x;
  int lane = tid & 63, w = tid >> 6;
  int row0 = blockIdx.x * 16;
  agg8_to_lds(ht, rc, col_idx, dis, bias, Hs, row0 + w * 8, w * 8, lane, n);
  __syncthreads();
  int rlane = lane & 15, g = lane >> 4;
  bf16x8 a0 = *(const bf16x8*)&Hs[rlane][g * 8];
  bf16x8 a1 = *(const bf16x8*)&Hs[rlane][g * 8 + 32];
#pragma unroll
  for (int tt = 0; tt < 2; ++tt) {
    int t = 2 * w + tt;
    bf16x8 b0 = *(const bf16x8*)(Wt + (rlane + 16 * t) * 64 + g * 8);
    bf16x8 b1 = *(const bf16x8*)(Wt + (rlane + 16 * t) * 64 + g * 8 + 32);
    f32x4 acc = (f32x4){0.f, 0.f, 0.f, 0.f};
    acc = __builtin_amdgcn_mfma_f32_16x16x32_bf16(a0, b0, acc, 0, 0, 0);
    acc = __builtin_amdgcn_mfma_f32_16x16x32_bf16(a1, b1, acc, 0, 0, 0);
#pragma unroll
    for (int r = 0; r < 4; ++r) {
      int gr = row0 + g * 4 + r;
      if (gr < n) out[(size_t)gr * 64 + rlane + 16 * t] = (short)f2b(acc[r] * dis[gr]);
    }
  }
}

// fused: agg -> MLP head -> log_softmax. 128 threads / 16 nodes / block.
// L1/L2 split across the 2 waves (ping-pong LDS); L3+softmax on wave 0.
static __global__ __launch_bounds__(128) void k_aggdense(const short* __restrict__ ht, const int2* __restrict__ rc,
    const int* __restrict__ col_idx, const float* __restrict__ dis, const float* __restrict__ bias,
    const short* __restrict__ W1t, const float* __restrict__ bf1,
    const short* __restrict__ W2t, const float* __restrict__ bf2,
    const short* __restrict__ W3t, const float* __restrict__ bf3,
    float* __restrict__ out, int n) {
  __shared__ __align__(16) short Hs[16][72];
  __shared__ __align__(16) short H2[16][72];
  int tid = threadIdx.x;
  int lane = tid & 63, w = tid >> 6;
  int row0 = blockIdx.x * 16;
  agg8_to_lds(ht, rc, col_idx, dis, bias, Hs, row0 + w * 8, w * 8, lane, n);
  __syncthreads();
  int rlane = lane & 15, g = lane >> 4;
  // L1: wave w computes col-tiles 2w, 2w+1 -> H2
  {
    bf16x8 a0 = *(const bf16x8*)&Hs[rlane][g * 8];
    bf16x8 a1 = *(const bf16x8*)&Hs[rlane][g * 8 + 32];
#pragma unroll
    for (int tt = 0; tt < 2; ++tt) {
      int t = 2 * w + tt;
      bf16x8 b0 = *(const bf16x8*)(W1t + (rlane + 16 * t) * 64 + g * 8);
      bf16x8 b1 = *(const bf16x8*)(W1t + (rlane + 16 * t) * 64 + g * 8 + 32);
      f32x4 acc = (f32x4){0.f, 0.f, 0.f, 0.f};
      acc = __builtin_amdgcn_mfma_f32_16x16x32_bf16(a0, b0, acc, 0, 0, 0);
      acc = __builtin_amdgcn_mfma_f32_16x16x32_bf16(a1, b1, acc, 0, 0, 0);
      float bb = bf1[16 * t + rlane];
#pragma unroll
      for (int r = 0; r < 4; ++r)
        H2[g * 4 + r][16 * t + rlane] = (short)f2b(fmaxf(acc[r] + bb, 0.f));
    }
  }
  __syncthreads();
  // L2: H2 -> Hs
  {
    bf16x8 c0 = *(const bf16x8*)&H2[rlane][g * 8];
    bf16x8 c1 = *(const bf16x8*)&H2[rlane][g * 8 + 32];
#pragma unroll
    for (int tt = 0; tt < 2; ++tt) {
      int t = 2 * w + tt;
      bf16x8 b0 = *(const bf16x8*)(W2t + (rlane + 16 * t) * 64 + g * 8);
      bf16x8 b1 = *(const bf16x8*)(W2t + (rlane + 16 * t) * 64 + g * 8 + 32);
      f32x4 acc = (f32x4){0.f, 0.f, 0.f, 0.f};
      acc = __builtin_amdgcn_mfma_f32_16x16x32_bf16(c0, b0, acc, 0, 0, 0);
      acc = __builtin_amdgcn_mfma_f32_16x16x32_bf16(c1, b1, acc, 0, 0, 0);
      float bb = bf2[16 * t + rlane];
#pragma unroll
      for (int r = 0; r < 4; ++r)
        Hs[g * 4 + r][16 * t + rlane] = (short)f2b(fmaxf(acc[r] + bb, 0.f));
    }
  }
  __syncthreads();
  // L3 + log_softmax: wave 0 only (16 output classes, one 16x16x64 job)
  if (w == 0) {
    bf16x8 d0 = *(const bf16x8*)&Hs[rlane][g * 8];
    bf16x8 d1 = *(const bf16x8*)&Hs[rlane][g * 8 + 32];
    bf16x8 e0 = *(const bf16x8*)(W3t + rlane * 64 + g * 8);
    bf16x8 e1 = *(const bf16x8*)(W3t + rlane * 64 + g * 8 + 32);
    f32x4 z = (f32x4){0.f, 0.f, 0.f, 0.f};
    z = __builtin_amdgcn_mfma_f32_16x16x32_bf16(d0, e0, z, 0, 0, 0);
    z = __builtin_amdgcn_mfma_f32_16x16x32_bf16(d1, e1, z, 0, 0, 0);
    float bsc = bf3[rlane];
#pragma unroll
    for (int r = 0; r < 4; ++r) {
      float zz = z[r] + bsc;
      float mx = zz;
      mx = fmaxf(mx, __shfl_xor(mx, 1));
      mx = fmaxf(mx, __shfl_xor(mx, 2));
      mx = fmaxf(mx, __shfl_xor(mx, 4));
      mx = fmaxf(mx, __shfl_xor(mx, 8));
      float ex = __expf(zz - mx);
      ex += __shfl_xor(ex, 1);
      ex += __shfl_xor(ex, 2);
      ex += __shfl_xor(ex, 4);
      ex += __shfl_xor(ex, 8);
      float lse = mx + __logf(ex);
      int gr = row0 + g * 4 + r;
      if (gr < n) out[(size_t)gr * 16 + rlane] = zz - lse;
    }
  }
}

extern "C" void kernel_launch(void* const* d_in, const int* in_sizes, int n_in,
                              void* d_out, int out_size, void* d_ws, size_t ws_size,
                              hipStream_t stream) {
  (void)in_sizes; (void)n_in; (void)out_size; (void)ws_size;
  const float* x   = (const float*)d_in[0];
  const int*   ei  = (const int*)d_in[1];
  const float* W1  = (const float*)d_in[2];
  const float* b1  = (const float*)d_in[3];
  const float* W2  = (const float*)d_in[4];
  const float* b2  = (const float*)d_in[5];
  const float* W3  = (const float*)d_in[6];
  const float* b3  = (const float*)d_in[7];
  const float* Wf1 = (const float*)d_in[8];
  const float* bf1 = (const float*)d_in[9];
  const float* Wf2 = (const float*)d_in[10];
  const float* bf2 = (const float*)d_in[11];
  const float* Wf3 = (const float*)d_in[12];
  const float* bf3 = (const float*)d_in[13];
  float* outp = (float*)d_out;
  const int* srcp = ei;
  const int* dstp = ei + NE;

  char* ws = (char*)d_ws;
  size_t off = 0;
  auto alloc = [&](size_t bytes) { void* p = ws + off; off = (off + bytes + 255) & ~(size_t)255; return p; };
  int2*  rc     = (int2*)alloc((size_t)NN * 8);
  float* dis    = (float*)alloc((size_t)NN * 4);
  int*   gcur   = (int*)alloc(256 * 4);
  int*   colidx = (int*)alloc((size_t)NBUK * BSTRIDE * 4);
  short* W1t    = (short*)alloc(4096 * 2);
  short* W2t    = (short*)alloc(4096 * 2);
  short* W3t    = (short*)alloc(4096 * 2);
  short* Wf1t   = (short*)alloc(4096 * 2);
  short* Wf2t   = (short*)alloc(4096 * 2);
  short* Wf3t   = (short*)alloc(1024 * 2);
  short* bufA   = (short*)alloc((size_t)NN * 64 * 2);
  short* bufB   = (short*)alloc((size_t)NN * 64 * 2);
  int*   ebuf   = (int*)alloc((size_t)NBUK * BSTRIDE * 4);

  int gMM = (NN + 63) / 64;      // 1563 (256-thread blocks)
  int gAG = (NN + 15) / 16;      // 6250 (128-thread blocks, 12500 waves)

  hipMemsetAsync(gcur, 0, 256 * 4, stream);
  k_scwc<<<EBLK + 6, 256, 0, stream>>>(srcp, dstp, gcur, ebuf,
                                       W1, W2, W3, Wf1, Wf2, Wf3,
                                       W1t, W2t, W3t, Wf1t, Wf2t, Wf3t);
  k_bucket<<<NBUK, 256, 0, stream>>>(ebuf, gcur, rc, dis, colidx);

  // ht1 = (x @ W1) * dis
  k_mm1<<<gMM, 256, 0, stream>>>(x, W1t, dis, bufB, NN);
  // h1 = relu(dis*(agg ht1) + b1); ht2 = (h1 @ W2) * dis
  k_aggmm<<<gAG, 128, 0, stream>>>(bufB, rc, colidx, dis, b1, W2t, bufA, NN);
  // h2 = relu(dis*(agg ht2) + b2); ht3 = (h2 @ W3) * dis
  k_aggmm<<<gAG, 128, 0, stream>>>(bufA, rc, colidx, dis, b2, W3t, bufB, NN);
  // h3 = relu(dis*(agg ht3) + b3); out = log_softmax(MLP(h3))
  k_aggdense<<<gAG, 128, 0, stream>>>(bufB, rc, colidx, dis, b3,
                                      Wf1t, bf1, Wf2t, bf2, Wf3t, bf3, outp, NN);
}

// Round 12
// 135.048 us; speedup vs baseline: 1.1343x; 1.0198x over previous
//
#include <hip/hip_runtime.h>
#include <hip/hip_bf16.h>

#define NN 100000
#define NE 800000
#define EBLK 391        // ceil(NE/2048)
#define NBUK 196        // ceil(NN/512), bucket = dst >> 9
#define BSTRIDE 6144    // fixed per-bucket capacity (expected 4082 +/- 64)

typedef __attribute__((ext_vector_type(8))) short bf16x8;
typedef __attribute__((ext_vector_type(4))) float f32x4;

__device__ __forceinline__ unsigned short f2b(float f) {
  unsigned int x = __float_as_uint(f);
  return (unsigned short)((x + 0x7fffu + ((x >> 16) & 1u)) >> 16);
}
__device__ __forceinline__ float b2f(short us) {
  return __uint_as_float(((unsigned int)(unsigned short)us) << 16);
}
__device__ __forceinline__ void acc8(float* acc, bf16x8 v) {
#pragma unroll
  for (int i = 0; i < 8; ++i) acc[i] += b2f(v[i]);
}

// ---------------- CSR build (2 kernels) + weight conversion merged ----------------
static __global__ __launch_bounds__(256) void k_scwc(const int* __restrict__ src, const int* __restrict__ dst,
                                                     int* __restrict__ gcur, int* __restrict__ ebuf,
    const float* __restrict__ W1, const float* __restrict__ W2, const float* __restrict__ W3,
    const float* __restrict__ Wf1, const float* __restrict__ Wf2, const float* __restrict__ Wf3,
    short* __restrict__ W1t, short* __restrict__ W2t, short* __restrict__ W3t,
    short* __restrict__ Wf1t, short* __restrict__ Wf2t, short* __restrict__ Wf3t) {
  int tid = threadIdx.x, blk = blockIdx.x;
  if (blk >= EBLK) {
    int b = blk - EBLK;
    if (b < 5) {
      const float* W = (b == 0) ? W1 : (b == 1) ? W2 : (b == 2) ? W3 : (b == 3) ? Wf1 : Wf2;
      short* Wt = (b == 0) ? W1t : (b == 1) ? W2t : (b == 2) ? W3t : (b == 3) ? Wf1t : Wf2t;
#pragma unroll
      for (int i = 0; i < 16; ++i) {
        int idx = tid + 256 * i;       // = k*64 + n
        int k = idx >> 6, nn = idx & 63;
        Wt[nn * 64 + k] = (short)f2b(W[idx]);
      }
    } else {
#pragma unroll
      for (int i = 0; i < 4; ++i) {
        int idx = tid + 256 * i;       // = k*16 + n
        int k = idx >> 4, nn = idx & 15;
        Wf3t[nn * 64 + k] = (short)f2b(Wf3[idx]);
      }
    }
    return;
  }
  __shared__ int hist[256];
  __shared__ int lstart[256];
  __shared__ int gbase[256];
  __shared__ int cur[NBUK];
  __shared__ int2 sbuf[2048];
  hist[tid] = 0;
  __syncthreads();
  int base = blk * 2048;
  int dd[8], ss[8];
#pragma unroll
  for (int i = 0; i < 8; ++i) {
    int e = base + tid + 256 * i;
    if (e < NE) {
      dd[i] = dst[e]; ss[i] = src[e];
      atomicAdd(&hist[dd[i] >> 9], 1);
    } else dd[i] = -1;
  }
  __syncthreads();
  int v = hist[tid];
  lstart[tid] = v;
  __syncthreads();
  for (int off = 1; off < 256; off <<= 1) {
    int t = (tid >= off) ? lstart[tid - off] : 0;
    __syncthreads();
    lstart[tid] += t;
    __syncthreads();
  }
  int excl = lstart[tid] - v;
  __syncthreads();
  lstart[tid] = excl;
  if (tid < NBUK) {
    cur[tid] = 0;
    gbase[tid] = (v > 0) ? atomicAdd(&gcur[tid], v) : 0;
  }
  __syncthreads();
#pragma unroll
  for (int i = 0; i < 8; ++i) {
    if (dd[i] >= 0) {
      int b = dd[i] >> 9;
      int p = atomicAdd(&cur[b], 1);
      sbuf[lstart[b] + p] = make_int2((ss[i] << 9) | (dd[i] & 511), b);
    }
  }
  __syncthreads();
  int m = NE - base; if (m > 2048) m = 2048;
#pragma unroll
  for (int i = 0; i < 8; ++i) {
    int j = tid + 256 * i;
    if (j < m) {
      int2 e = sbuf[j];
      int b = e.y;
      int gpos = b * BSTRIDE + gbase[b] + (j - lstart[b]);
      ebuf[gpos] = e.x;
    }
  }
}

static __global__ __launch_bounds__(256) void k_bucket(const int* __restrict__ ebuf, const int* __restrict__ gcur,
                                                       int4* __restrict__ rc4, float* __restrict__ dis,
                                                       int* __restrict__ col_idx) {
  __shared__ int cnt[512];
  __shared__ int lrs[512];
  __shared__ int sd[256];
  int b = blockIdx.x, tid = threadIdx.x;
  int base_n = b << 9;
  int ebeg = b * BSTRIDE;
  int m = gcur[b];
  cnt[tid] = 0; cnt[tid + 256] = 0;
  __syncthreads();
  for (int j = tid; j < m; j += 256) atomicAdd(&cnt[ebuf[ebeg + j] & 511], 1);
  __syncthreads();
  int v0 = cnt[2 * tid], v1 = cnt[2 * tid + 1];
  int s = v0 + v1;
  sd[tid] = s;
  __syncthreads();
  for (int off = 1; off < 256; off <<= 1) {
    int t = (tid >= off) ? sd[tid - off] : 0;
    __syncthreads();
    sd[tid] += t;
    __syncthreads();
  }
  int excl = sd[tid] - s;
  lrs[2 * tid] = excl;
  lrs[2 * tid + 1] = excl + v0;
  __syncthreads();
  for (int i = tid; i < 512; i += 256) {
    int n = base_n + i;
    if (n < NN) {
      int c = cnt[i];
      float d = 1.0f / sqrtf((float)c + 1.0f);
      rc4[n] = make_int4(ebeg + lrs[i], c, __float_as_int(d), 0);
      dis[n] = d;
    }
  }
  for (int i = tid; i < 512; i += 256) cnt[i] = lrs[i];
  __syncthreads();
  for (int j = tid; j < m; j += 256) {
    int e = ebuf[ebeg + j];
    int p = atomicAdd(&cnt[e & 511], 1);
    col_idx[ebeg + p] = e >> 9;
  }
}

__device__ __forceinline__ bf16x8 load_a_frag_f32(const float* __restrict__ p, bool valid) {
  float4 f0 = valid ? *(const float4*)p : make_float4(0.f, 0.f, 0.f, 0.f);
  float4 f1 = valid ? *(const float4*)(p + 4) : make_float4(0.f, 0.f, 0.f, 0.f);
  bf16x8 a;
  a[0] = (short)f2b(f0.x); a[1] = (short)f2b(f0.y); a[2] = (short)f2b(f0.z); a[3] = (short)f2b(f0.w);
  a[4] = (short)f2b(f1.x); a[5] = (short)f2b(f1.y); a[6] = (short)f2b(f1.z); a[7] = (short)f2b(f1.w);
  return a;
}

// shared MFMA body: writes ht (bf16, dis-scaled)
__device__ __forceinline__ void mm_body(bf16x8 a0, bf16x8 a1, const short* __restrict__ Wt,
                                        const float* __restrict__ dis, short* __restrict__ out,
                                        int row0, int rlane, int g, int n) {
  f32x4 acc[4];
#pragma unroll
  for (int t = 0; t < 4; ++t) acc[t] = (f32x4){0.f, 0.f, 0.f, 0.f};
#pragma unroll
  for (int t = 0; t < 4; ++t) {
    bf16x8 b0 = *(const bf16x8*)(Wt + (rlane + 16 * t) * 64 + g * 8);
    bf16x8 b1 = *(const bf16x8*)(Wt + (rlane + 16 * t) * 64 + g * 8 + 32);
    acc[t] = __builtin_amdgcn_mfma_f32_16x16x32_bf16(a0, b0, acc[t], 0, 0, 0);
    acc[t] = __builtin_amdgcn_mfma_f32_16x16x32_bf16(a1, b1, acc[t], 0, 0, 0);
  }
#pragma unroll
  for (int r = 0; r < 4; ++r) {
    int gr = row0 + g * 4 + r;
    if (gr < n) {
      float s = dis[gr];
#pragma unroll
      for (int t = 0; t < 4; ++t)
        out[(size_t)gr * 64 + rlane + 16 * t] = (short)f2b(acc[t][r] * s);
    }
  }
}

// layer-1: f32 input, ht1 = (x @ W1) * dis
static __global__ __launch_bounds__(256) void k_mm1(const float* __restrict__ in, const short* __restrict__ Wt,
                                                    const float* __restrict__ dis, short* __restrict__ out, int n) {
  int tid = threadIdx.x;
  int lane = tid & 63, w = tid >> 6;
  int row0 = blockIdx.x * 64 + w * 16;
  int rlane = lane & 15, g = lane >> 4;
  int arow = row0 + rlane;
  bool av = arow < n;
  const float* ap = in + (size_t)arow * 64 + g * 8;
  bf16x8 a0 = load_a_frag_f32(ap, av);
  bf16x8 a1 = load_a_frag_f32(ap + 32, av);
  mm_body(a0, a1, Wt, dis, out, row0, rlane, g, n);
}

// agg: ONE node per 8-lane group, 8 nodes/wave. Per 8-edge chunk: broadcast all
// 8 indices, issue ALL 8 row-loads (invalid -> row 0, cache-hot), wait once,
// accumulate guarded. One latency exposure per chunk (deg<=8 => one total).
__device__ __forceinline__ void agg8_to_lds(const short* __restrict__ ht, const int4* __restrict__ rc4,
                                            const int* __restrict__ col_idx,
                                            const float* __restrict__ bias, short (*Hs)[72],
                                            int nodebase, int wrow0, int lane, int n) {
  int g = lane >> 3, f = lane & 7;
  float4 b0v = *(const float4*)&bias[f * 8];
  float4 b1v = *(const float4*)&bias[f * 8 + 4];
  float bb[8] = {b0v.x, b0v.y, b0v.z, b0v.w, b1v.x, b1v.y, b1v.z, b1v.w};
  int node = nodebase + g;
  bool nv = node < n;
  int4 rcv = nv ? rc4[node] : make_int4(0, 0, 0, 0);
  int beg = rcv.x, cnt = rcv.y;
  float ds = nv ? __int_as_float(rcv.z) : 0.f;
  float acc[8] = {0.f, 0.f, 0.f, 0.f, 0.f, 0.f, 0.f, 0.f};
  if (nv) acc8(acc, *(const bf16x8*)(ht + (size_t)node * 64 + f * 8));   // self-loop
  for (int base = 0; base < cnt; base += 8) {
    int idx = (base + f < cnt) ? col_idx[beg + base + f] : 0;
    int s[8];
#pragma unroll
    for (int e = 0; e < 8; ++e) s[e] = __shfl(idx, g * 8 + e);
    bf16x8 r[8];
#pragma unroll
    for (int e = 0; e < 8; ++e) r[e] = *(const bf16x8*)(ht + (size_t)s[e] * 64 + f * 8);
    int mm = cnt - base; if (mm > 8) mm = 8;
#pragma unroll
    for (int e = 0; e < 8; ++e) { if (e < mm) acc8(acc, r[e]); }
  }
  bf16x8 o;
#pragma unroll
  for (int i = 0; i < 8; ++i)
    o[i] = (short)f2b(fmaxf(fmaf(ds, acc[i], bb[i]), 0.f));
  *(bf16x8*)&Hs[wrow0 + g][f * 8] = o;
}

// fused: agg -> matmul. 128 threads / 16 nodes / block (grid 6250 = 12500 waves).
static __global__ __launch_bounds__(128) void k_aggmm(const short* __restrict__ ht, const int4* __restrict__ rc4,
                                                      const int* __restrict__ col_idx, const float* __restrict__ dis,
                                                      const float* __restrict__ bias, const short* __restrict__ Wt,
                                                      short* __restrict__ out, int n) {
  __shared__ __align__(16) short Hs[16][72];
  int tid = threadIdx.x;
  int lane = tid & 63, w = tid >> 6;
  int row0 = blockIdx.x * 16;
  agg8_to_lds(ht, rc4, col_idx, bias, Hs, row0 + w * 8, w * 8, lane, n);
  __syncthreads();
  int rlane = lane & 15, g = lane >> 4;
  bf16x8 a0 = *(const bf16x8*)&Hs[rlane][g * 8];
  bf16x8 a1 = *(const bf16x8*)&Hs[rlane][g * 8 + 32];
#pragma unroll
  for (int tt = 0; tt < 2; ++tt) {
    int t = 2 * w + tt;
    bf16x8 b0 = *(const bf16x8*)(Wt + (rlane + 16 * t) * 64 + g * 8);
    bf16x8 b1 = *(const bf16x8*)(Wt + (rlane + 16 * t) * 64 + g * 8 + 32);
    f32x4 acc = (f32x4){0.f, 0.f, 0.f, 0.f};
    acc = __builtin_amdgcn_mfma_f32_16x16x32_bf16(a0, b0, acc, 0, 0, 0);
    acc = __builtin_amdgcn_mfma_f32_16x16x32_bf16(a1, b1, acc, 0, 0, 0);
#pragma unroll
    for (int r = 0; r < 4; ++r) {
      int gr = row0 + g * 4 + r;
      if (gr < n) out[(size_t)gr * 64 + rlane + 16 * t] = (short)f2b(acc[r] * dis[gr]);
    }
  }
}

// fused: agg -> MLP head -> log_softmax. 128 threads / 16 nodes / block.
static __global__ __launch_bounds__(128) void k_aggdense(const short* __restrict__ ht, const int4* __restrict__ rc4,
    const int* __restrict__ col_idx, const float* __restrict__ bias,
    const short* __restrict__ W1t, const float* __restrict__ bf1,
    const short* __restrict__ W2t, const float* __restrict__ bf2,
    const short* __restrict__ W3t, const float* __restrict__ bf3,
    float* __restrict__ out, int n) {
  __shared__ __align__(16) short Hs[16][72];
  __shared__ __align__(16) short H2[16][72];
  int tid = threadIdx.x;
  int lane = tid & 63, w = tid >> 6;
  int row0 = blockIdx.x * 16;
  agg8_to_lds(ht, rc4, col_idx, bias, Hs, row0 + w * 8, w * 8, lane, n);
  __syncthreads();
  int rlane = lane & 15, g = lane >> 4;
  // L1: wave w computes col-tiles 2w, 2w+1 -> H2
  {
    bf16x8 a0 = *(const bf16x8*)&Hs[rlane][g * 8];
    bf16x8 a1 = *(const bf16x8*)&Hs[rlane][g * 8 + 32];
#pragma unroll
    for (int tt = 0; tt < 2; ++tt) {
      int t = 2 * w + tt;
      bf16x8 b0 = *(const bf16x8*)(W1t + (rlane + 16 * t) * 64 + g * 8);
      bf16x8 b1 = *(const bf16x8*)(W1t + (rlane + 16 * t) * 64 + g * 8 + 32);
      f32x4 acc = (f32x4){0.f, 0.f, 0.f, 0.f};
      acc = __builtin_amdgcn_mfma_f32_16x16x32_bf16(a0, b0, acc, 0, 0, 0);
      acc = __builtin_amdgcn_mfma_f32_16x16x32_bf16(a1, b1, acc, 0, 0, 0);
      float bb = bf1[16 * t + rlane];
#pragma unroll
      for (int r = 0; r < 4; ++r)
        H2[g * 4 + r][16 * t + rlane] = (short)f2b(fmaxf(acc[r] + bb, 0.f));
    }
  }
  __syncthreads();
  // L2: H2 -> Hs
  {
    bf16x8 c0 = *(const bf16x8*)&H2[rlane][g * 8];
    bf16x8 c1 = *(const bf16x8*)&H2[rlane][g * 8 + 32];
#pragma unroll
    for (int tt = 0; tt < 2; ++tt) {
      int t = 2 * w + tt;
      bf16x8 b0 = *(const bf16x8*)(W2t + (rlane + 16 * t) * 64 + g * 8);
      bf16x8 b1 = *(const bf16x8*)(W2t + (rlane + 16 * t) * 64 + g * 8 + 32);
      f32x4 acc = (f32x4){0.f, 0.f, 0.f, 0.f};
      acc = __builtin_amdgcn_mfma_f32_16x16x32_bf16(c0, b0, acc, 0, 0, 0);
      acc = __builtin_amdgcn_mfma_f32_16x16x32_bf16(c1, b1, acc, 0, 0, 0);
      float bb = bf2[16 * t + rlane];
#pragma unroll
      for (int r = 0; r < 4; ++r)
        Hs[g * 4 + r][16 * t + rlane] = (short)f2b(fmaxf(acc[r] + bb, 0.f));
    }
  }
  __syncthreads();
  // L3 + log_softmax: wave 0 only
  if (w == 0) {
    bf16x8 d0 = *(const bf16x8*)&Hs[rlane][g * 8];
    bf16x8 d1 = *(const bf16x8*)&Hs[rlane][g * 8 + 32];
    bf16x8 e0 = *(const bf16x8*)(W3t + rlane * 64 + g * 8);
    bf16x8 e1 = *(const bf16x8*)(W3t + rlane * 64 + g * 8 + 32);
    f32x4 z = (f32x4){0.f, 0.f, 0.f, 0.f};
    z = __builtin_amdgcn_mfma_f32_16x16x32_bf16(d0, e0, z, 0, 0, 0);
    z = __builtin_amdgcn_mfma_f32_16x16x32_bf16(d1, e1, z, 0, 0, 0);
    float bsc = bf3[rlane];
#pragma unroll
    for (int r = 0; r < 4; ++r) {
      float zz = z[r] + bsc;
      float mx = zz;
      mx = fmaxf(mx, __shfl_xor(mx, 1));
      mx = fmaxf(mx, __shfl_xor(mx, 2));
      mx = fmaxf(mx, __shfl_xor(mx, 4));
      mx = fmaxf(mx, __shfl_xor(mx, 8));
      float ex = __expf(zz - mx);
      ex += __shfl_xor(ex, 1);
      ex += __shfl_xor(ex, 2);
      ex += __shfl_xor(ex, 4);
      ex += __shfl_xor(ex, 8);
      float lse = mx + __logf(ex);
      int gr = row0 + g * 4 + r;
      if (gr < n) out[(size_t)gr * 16 + rlane] = zz - lse;
    }
  }
}

extern "C" void kernel_launch(void* const* d_in, const int* in_sizes, int n_in,
                              void* d_out, int out_size, void* d_ws, size_t ws_size,
                              hipStream_t stream) {
  (void)in_sizes; (void)n_in; (void)out_size; (void)ws_size;
  const float* x   = (const float*)d_in[0];
  const int*   ei  = (const int*)d_in[1];
  const float* W1  = (const float*)d_in[2];
  const float* b1  = (const float*)d_in[3];
  const float* W2  = (const float*)d_in[4];
  const float* b2  = (const float*)d_in[5];
  const float* W3  = (const float*)d_in[6];
  const float* b3  = (const float*)d_in[7];
  const float* Wf1 = (const float*)d_in[8];
  const float* bf1 = (const float*)d_in[9];
  const float* Wf2 = (const float*)d_in[10];
  const float* bf2 = (const float*)d_in[11];
  const float* Wf3 = (const float*)d_in[12];
  const float* bf3 = (const float*)d_in[13];
  float* outp = (float*)d_out;
  const int* srcp = ei;
  const int* dstp = ei + NE;

  char* ws = (char*)d_ws;
  size_t off = 0;
  auto alloc = [&](size_t bytes) { void* p = ws + off; off = (off + bytes + 255) & ~(size_t)255; return p; };
  int4*  rc4    = (int4*)alloc((size_t)NN * 16);
  float* dis    = (float*)alloc((size_t)NN * 4);
  int*   gcur   = (int*)alloc(256 * 4);
  int*   colidx = (int*)alloc((size_t)NBUK * BSTRIDE * 4);
  short* W1t    = (short*)alloc(4096 * 2);
  short* W2t    = (short*)alloc(4096 * 2);
  short* W3t    = (short*)alloc(4096 * 2);
  short* Wf1t   = (short*)alloc(4096 * 2);
  short* Wf2t   = (short*)alloc(4096 * 2);
  short* Wf3t   = (short*)alloc(1024 * 2);
  short* bufA   = (short*)alloc((size_t)NN * 64 * 2);
  short* bufB   = (short*)alloc((size_t)NN * 64 * 2);
  int*   ebuf   = (int*)alloc((size_t)NBUK * BSTRIDE * 4);

  int gMM = (NN + 63) / 64;      // 1563 (256-thread blocks)
  int gAG = (NN + 15) / 16;      // 6250 (128-thread blocks, 12500 waves)

  hipMemsetAsync(gcur, 0, 256 * 4, stream);
  k_scwc<<<EBLK + 6, 256, 0, stream>>>(srcp, dstp, gcur, ebuf,
                                       W1, W2, W3, Wf1, Wf2, Wf3,
                                       W1t, W2t, W3t, Wf1t, Wf2t, Wf3t);
  k_bucket<<<NBUK, 256, 0, stream>>>(ebuf, gcur, rc4, dis, colidx);

  // ht1 = (x @ W1) * dis
  k_mm1<<<gMM, 256, 0, stream>>>(x, W1t, dis, bufB, NN);
  // h1 = relu(dis*(agg ht1) + b1); ht2 = (h1 @ W2) * dis
  k_aggmm<<<gAG, 128, 0, stream>>>(bufB, rc4, colidx, dis, b1, W2t, bufA, NN);
  // h2 = relu(dis*(agg ht2) + b2); ht3 = (h2 @ W3) * dis
  k_aggmm<<<gAG, 128, 0, stream>>>(bufA, rc4, colidx, dis, b2, W3t, bufB, NN);
  // h3 = relu(dis*(agg ht3) + b3); out = log_softmax(MLP(h3))
  k_aggdense<<<gAG, 128, 0, stream>>>(bufB, rc4, colidx, b3,
                                      Wf1t, bf1, Wf2t, bf2, Wf3t, bf3, outp, NN);
}